// Round 2
// baseline (22210.759 us; speedup 1.0000x reference)
//
#include <hip/hip_runtime.h>
#include <math.h>

// Problem constants
#define NB_ 64          // GJ block size (was 32; 64 halves update-pass M traffic)
#define NPH 8           // 512 / NB_
// B=32, L=512, H=768, T=8, DK=96, BT=256

// ---------------------------------------------------------------------------
// 1) Q/K projection: out[m][n] = x[m][:] . W[n][:] + bias[n]   (W row-major, "NT")
//    BM=128, BN=64, BK=16, 256 threads, 8x4 micro-tile. grid.z selects Wq/Wk.
//    Micro-tile remapped: thread owns rows {tm*4+i, 64+tm*4+i} so LDS reads sit
//    at 16B lane spacing (2-way = free) instead of 32B (4-way conflict).
// ---------------------------------------------------------------------------
__global__ __launch_bounds__(256) void proj_gemm(const float* __restrict__ x,
    const float* __restrict__ Wq, const float* __restrict__ bq,
    const float* __restrict__ Wk, const float* __restrict__ bk,
    float* __restrict__ Qb, float* __restrict__ Kb) {
  const float* W    = blockIdx.z ? Wk : Wq;
  const float* bias = blockIdx.z ? bk : bq;
  float* out        = blockIdx.z ? Kb : Qb;
  const int m0 = blockIdx.x * 128;
  const int n0 = blockIdx.y * 64;
  __shared__ float Xs[16][132];   // [k][m], stride 132 keeps f4 alignment + bank spread
  __shared__ float Ws[16][68];    // [k][n]
  const int tid = threadIdx.x;
  const int tm = tid & 15, tn = tid >> 4;   // both [0,16)
  float acc[8][4];
#pragma unroll
  for (int i = 0; i < 8; i++)
#pragma unroll
    for (int j = 0; j < 4; j++) acc[i][j] = 0.f;

  for (int kk = 0; kk < 768; kk += 16) {
    // load X tile 128x16 (512 float4)
#pragma unroll
    for (int rep = 0; rep < 2; rep++) {
      int fidx = tid + rep * 256;
      int row = fidx >> 2, f4i = fidx & 3;
      float4 v = ((const float4*)(x + (size_t)(m0 + row) * 768 + kk))[f4i];
      Xs[f4i * 4 + 0][row] = v.x; Xs[f4i * 4 + 1][row] = v.y;
      Xs[f4i * 4 + 2][row] = v.z; Xs[f4i * 4 + 3][row] = v.w;
    }
    { // load W tile 64x16 (256 float4)
      int row = tid >> 2, f4i = tid & 3;
      float4 v = ((const float4*)(W + (size_t)(n0 + row) * 768 + kk))[f4i];
      Ws[f4i * 4 + 0][row] = v.x; Ws[f4i * 4 + 1][row] = v.y;
      Ws[f4i * 4 + 2][row] = v.z; Ws[f4i * 4 + 3][row] = v.w;
    }
    __syncthreads();
#pragma unroll
    for (int k = 0; k < 16; k++) {
      float4 a0 = *(const float4*)&Xs[k][tm * 4];        // banks 4tm..: 2-way, free
      float4 a1 = *(const float4*)&Xs[k][tm * 4 + 64];   // same pattern
      float4 bv = *(const float4*)&Ws[k][tn * 4];        // wave-uniform broadcast
      float am[8] = {a0.x,a0.y,a0.z,a0.w,a1.x,a1.y,a1.z,a1.w};
      float bn[4] = {bv.x,bv.y,bv.z,bv.w};
#pragma unroll
      for (int i = 0; i < 8; i++)
#pragma unroll
        for (int j = 0; j < 4; j++) acc[i][j] += am[i] * bn[j];
    }
    __syncthreads();
  }
  float b0 = bias[n0 + tn * 4 + 0], b1 = bias[n0 + tn * 4 + 1];
  float b2 = bias[n0 + tn * 4 + 2], b3 = bias[n0 + tn * 4 + 3];
#pragma unroll
  for (int i = 0; i < 4; i++) {
    float4 o = {acc[i][0] + b0, acc[i][1] + b1, acc[i][2] + b2, acc[i][3] + b3};
    *(float4*)(out + (size_t)(m0 + tm * 4 + i) * 768 + n0 + tn * 4) = o;
    float4 o2 = {acc[i+4][0] + b0, acc[i+4][1] + b1, acc[i+4][2] + b2, acc[i+4][3] + b3};
    *(float4*)(out + (size_t)(m0 + 64 + tm * 4 + i) * 768 + n0 + tn * 4) = o2;
  }
}

// ---------------------------------------------------------------------------
// 2) f[b,t,l] = x[b,l,:] . Wroot[t,:] + broot[t]
// ---------------------------------------------------------------------------
__global__ __launch_bounds__(256) void f_kernel(const float* __restrict__ x,
    const float* __restrict__ Wroot, const float* __restrict__ broot,
    float* __restrict__ fout) {
  int row = blockIdx.x * 256 + threadIdx.x;   // b*512+l
  int b = row >> 9, l = row & 511;
  float acc[8] = {0,0,0,0,0,0,0,0};
  const float4* xr = (const float4*)(x + (size_t)row * 768);
  for (int h4 = 0; h4 < 192; h4++) {
    float4 xv = xr[h4];
#pragma unroll
    for (int t = 0; t < 8; t++) {
      float4 wv = ((const float4*)(Wroot + (size_t)t * 768))[h4];
      acc[t] += xv.x * wv.x + xv.y * wv.y + xv.z * wv.z + xv.w * wv.w;
    }
  }
#pragma unroll
  for (int t = 0; t < 8; t++)
    fout[(size_t)((b * 8 + t) << 9) + l] = acc[t] + broot[t];
}

// ---------------------------------------------------------------------------
// 3) scores -> softmax -> A = exp(p)*(1-eye), written to d_out.
//    Register-lean inner loop (acc[16] + one kv float4); XCD-chunked grid.
// ---------------------------------------------------------------------------
__global__ __launch_bounds__(256) void scores_kernel(const float* __restrict__ Qb,
    const float* __restrict__ Kb, const int* __restrict__ mask,
    float* __restrict__ A) {
  const int lin = blockIdx.x;                 // 8192 blocks
  const int xcd = lin & 7;
  const int idx = lin >> 3;                   // 0..1023 within XCD
  const int bt  = xcd * 32 + (idx >> 5);      // 32 bt per XCD, contiguous
  const int q0  = (idx & 31) * 16;
  const int b = bt >> 3, t = bt & 7;
  __shared__ float  S[16][512];
  __shared__ float4 Qs4[16][24];              // Q tile as float4 [q][d4]
  __shared__ float  part[16][16];
  __shared__ float  invsum[16];
  const int tid = threadIdx.x;
  for (int i = tid; i < 384; i += 256) {      // 16*24 float4
    int q = i / 24, f4 = i % 24;
    Qs4[q][f4] =
        ((const float4*)(Qb + (size_t)(b * 512 + q0 + q) * 768 + t * 96))[f4];
  }
  __syncthreads();
  const float scl = 0.10206207261596575f;     // 1/sqrt(96)
#pragma unroll 1
  for (int rep = 0; rep < 2; rep++) {
    const int k = rep * 256 + tid;
    const float4* kr = (const float4*)(Kb + (size_t)(b * 512 + k) * 768 + t * 96);
    float acc[16];
#pragma unroll
    for (int q = 0; q < 16; q++) acc[q] = 0.f;
#pragma unroll 4
    for (int f4 = 0; f4 < 24; f4++) {
      float4 kv = kr[f4];
#pragma unroll
      for (int q = 0; q < 16; q++) {
        float4 qv = Qs4[q][f4];               // wave-uniform -> LDS broadcast
        acc[q] += qv.x * kv.x + qv.y * kv.y + qv.z * kv.z + qv.w * kv.w;
      }
    }
    int mk = mask[b * 512 + k];
#pragma unroll
    for (int q = 0; q < 16; q++)
      S[q][k] = mk ? expf(acc[q] * scl) : 0.f;
  }
  __syncthreads();
  { // row sums; k = j + 16*i keeps lanes on 16 distinct banks (4-way max)
    int q = tid >> 4, j = tid & 15;
    float s = 0.f;
#pragma unroll
    for (int i = 0; i < 32; i++) s += S[q][j + 16 * i];
    part[q][j] = s;
  }
  __syncthreads();
  if (tid < 16) {
    float s = 0.f;
#pragma unroll
    for (int j = 0; j < 16; j++) s += part[tid][j];
    invsum[tid] = 1.f / fmaxf(s, 1e-30f);
  }
  __syncthreads();
#pragma unroll 1
  for (int rep = 0; rep < 2; rep++) {
    const int k = rep * 256 + tid;
#pragma unroll
    for (int q = 0; q < 16; q++) {
      float p = S[q][k] * invsum[q];
      float a = (q0 + q == k) ? 0.f : expf(p);
      A[(size_t)(bt * 512 + q0 + q) * 512 + k] = a;
    }
  }
}

// 4) deg[bt][k] = sum_q A[bt][q][k]
__global__ __launch_bounds__(256) void deg_kernel(const float* __restrict__ A,
                                                  float* __restrict__ deg) {
  int bt = blockIdx.y, k = blockIdx.x * 256 + threadIdx.x;
  const float* Ab = A + (size_t)bt * 262144;
  float s = 0.f;
  for (int q = 0; q < 512; q++) s += Ab[(size_t)q * 512 + k];
  deg[bt * 512 + k] = s;
}

// 5) M = Lbar:  row0 = f ; else -A + deg on diag
__global__ __launch_bounds__(128) void build_kernel(const float* __restrict__ A,
    const float* __restrict__ fin, const float* __restrict__ deg,
    float* __restrict__ M) {
  int q = blockIdx.x, bt = blockIdx.y, tid = threadIdx.x;
  size_t base = (size_t)bt * 262144;
  float4* Mo = (float4*)(M + base + (size_t)q * 512);
  if (q == 0) {
    Mo[tid] = ((const float4*)(fin + (size_t)bt * 512))[tid];
  } else {
    float4 a = ((const float4*)(A + base + (size_t)q * 512))[tid];
    float4 m = {-a.x, -a.y, -a.z, -a.w};
    int k0 = tid * 4;
    if (q >= k0 && q < k0 + 4) {
      float d = deg[bt * 512 + q];
      if      (q == k0    ) m.x += d;
      else if (q == k0 + 1) m.y += d;
      else if (q == k0 + 2) m.z += d;
      else                  m.w += d;
    }
    Mo[tid] = m;
  }
}

// ---------------------------------------------------------------------------
// 6a) Panel factorization: in-place GJ with partial pivoting over 64 pivot
//     columns. 512 threads, ONE row per thread (r[64] = 64 VGPR). Pivot
//     sequence identical to unblocked GJ w/ partial pivoting.
// ---------------------------------------------------------------------------
__global__ __launch_bounds__(512) void panel_kernel(float* __restrict__ M,
                                                    int* __restrict__ pivr, int ph) {
  const int bt = blockIdx.x, tid = threadIdx.x;
  const int j0 = ph * NB_;
  __shared__ float rowj[NB_];
  __shared__ float bufj[NB_], bufr[NB_];
  __shared__ float pivval_s;
  __shared__ unsigned long long wred[8];
  __shared__ int pivlist[NB_];
  float* Mb = M + (size_t)bt * 262144;
  float r[NB_];
  {
    const float4* p0 = (const float4*)(Mb + (size_t)tid * 512 + j0);
#pragma unroll
    for (int fi = 0; fi < 16; fi++) {
      float4 a = p0[fi];
      r[4*fi] = a.x; r[4*fi+1] = a.y; r[4*fi+2] = a.z; r[4*fi+3] = a.w;
    }
  }
  const int lane = tid & 63, wv = tid >> 6;
  for (int l = 0; l < NB_; l++) {
    const int j = j0 + l;
    // extract column-l value of my row (pre-swap)
    float v = 0.f;
#pragma unroll
    for (int c = 0; c < NB_; c++) v = (c == l) ? r[c] : v;
    // pivot search over rows >= j
    float best = -1.f; int bidx = 0;
    if (tid >= j) { best = fabsf(v); bidx = tid; }
    unsigned long long pk = (best >= 0.f)
        ? ((((unsigned long long)__float_as_uint(best)) << 32) | (unsigned)bidx) : 0ull;
#pragma unroll
    for (int off = 32; off > 0; off >>= 1) {
      unsigned long long o = __shfl_xor(pk, off, 64);
      if (o > pk) pk = o;
    }
    if (lane == 0) wred[wv] = pk;
    __syncthreads();
    unsigned long long ma = wred[0];
#pragma unroll
    for (int w = 1; w < 8; w++) ma = (wred[w] > ma) ? wred[w] : ma;
    const int rr = (int)(unsigned)(ma & 0xffffffffull);
    // stage swap rows + pivot value
    if (tid == rr) {
      pivval_s = v;
#pragma unroll
      for (int c = 0; c < NB_; c++) bufr[c] = r[c];
    }
    if (tid == j) {
#pragma unroll
      for (int c = 0; c < NB_; c++) bufj[c] = r[c];
    }
    if (tid == 0) pivlist[l] = rr;
    __syncthreads();
    const float rinv = 1.f / pivval_s;
    if (tid == j) {     // new pivot row = (old row rr)/p, col l -> 1/p
#pragma unroll
      for (int c = 0; c < NB_; c++) {
        float nv = (c == l) ? rinv : bufr[c] * rinv;
        r[c] = nv;
        rowj[c] = nv;
      }
    }
    if (rr != j && tid == rr) {  // row rr <- old row j
#pragma unroll
      for (int c = 0; c < NB_; c++) r[c] = bufj[c];
    }
    __syncthreads();
    // eliminate all rows != j (full GJ update, in-place column rule)
    if (tid != j) {
      float m = 0.f;
#pragma unroll
      for (int c = 0; c < NB_; c++) m = (c == l) ? r[c] : m;
#pragma unroll
      for (int c = 0; c < NB_; c++) r[c] = ((c == l) ? 0.f : r[c]) - m * rowj[c];
    }
    __syncthreads();
  }
  { // write back panel
    float4* p0 = (float4*)(Mb + (size_t)tid * 512 + j0);
#pragma unroll
    for (int fi = 0; fi < 16; fi++) {
      float4 a = {r[4*fi], r[4*fi+1], r[4*fi+2], r[4*fi+3]};
      p0[fi] = a;
    }
  }
  if (tid < NB_) pivr[bt * 512 + j0 + tid] = pivlist[tid];
}

// ---------------------------------------------------------------------------
// 6b) Rest-of-matrix update: X <- X[perm] + (panel - I_block) * X[perm][blockrows]
//     1-D XCD-chunked grid: the 8 col-tile blocks of one bt land on one XCD
//     so the 128KB panel is L2-shared. Panel columns skipped (already final).
// ---------------------------------------------------------------------------
__global__ __launch_bounds__(256) void update_kernel(float* __restrict__ M,
                                                     const int* __restrict__ pivr, int ph) {
  const int lin = blockIdx.x;                 // 2048 blocks
  const int xcd = lin & 7;
  const int idx = lin >> 3;                   // 0..255 within XCD
  const int bt  = xcd * 32 + (idx >> 3);      // 32 bt per XCD
  const int t0  = (idx & 7) * 64;
  const int j0 = ph * NB_;
  __shared__ int perm_s[512];
  __shared__ short rowslot_s[512];
  __shared__ float Xb[NB_][64];
  __shared__ float staged[128][64];           // 64 transpositions touch <=128 rows
  __shared__ int srcrow[128];
  __shared__ int cnt;
  const int tid = threadIdx.x;
  const int c = tid & 63, g = tid >> 6;
  float* Mb = M + (size_t)bt * 262144;
  for (int i = tid; i < 512; i += 256) { perm_s[i] = i; rowslot_s[i] = -1; }
  if (tid == 0) cnt = 0;
  __syncthreads();
  if (tid == 0) {
    for (int l = 0; l < NB_; l++) {
      int r = pivr[bt * 512 + j0 + l];
      int tp = perm_s[j0 + l]; perm_s[j0 + l] = perm_s[r]; perm_s[r] = tp;
    }
  }
  __syncthreads();
  for (int i = tid; i < 512; i += 256) {
    if (perm_s[i] != i) { int s = atomicAdd(&cnt, 1); rowslot_s[i] = (short)s; srcrow[s] = perm_s[i]; }
  }
  __syncthreads();
  const int nmv = cnt;   // <= 128
  for (int s = g; s < nmv; s += 4) staged[s][c] = Mb[(size_t)srcrow[s] * 512 + t0 + c];
  for (int l = g; l < NB_; l += 4) Xb[l][c] = Mb[(size_t)perm_s[j0 + l] * 512 + t0 + c];
  __syncthreads();
  float xb[NB_];
#pragma unroll
  for (int l = 0; l < NB_; l++) xb[l] = Xb[l][c];
  const int col = t0 + c;
  const bool colok = !(col >= j0 && col < j0 + NB_);
  for (int i = g * 128; i < g * 128 + 128; i++) {
    const float4* vp = (const float4*)(Mb + (size_t)i * 512 + j0);
    int rs = rowslot_s[i];
    float s = (rs >= 0) ? staged[rs][c] : Mb[(size_t)i * 512 + col];
#pragma unroll 8
    for (int fi = 0; fi < 16; fi++) {
      float4 v = vp[fi];
      s += v.x * xb[4*fi] + v.y * xb[4*fi+1] + v.z * xb[4*fi+2] + v.w * xb[4*fi+3];
    }
    if (i >= j0 && i < j0 + NB_) {     // subtract identity part of V
      int li = i - j0;
      float xs = 0.f;
#pragma unroll
      for (int l = 0; l < NB_; l++) xs = (l == li) ? xb[l] : xs;
      s -= xs;
    }
    if (colok) Mb[(size_t)i * 512 + col] = s;
  }
}

// 7) column unscramble map + diagonal of LLinv
__global__ __launch_bounds__(64) void colsrc_kernel(const float* __restrict__ M,
    const int* __restrict__ pivr, int* __restrict__ colsrc, float* __restrict__ diagv) {
  const int bt = blockIdx.x, tid = threadIdx.x;
  __shared__ int piv[512];
  __shared__ int cs[512];
  for (int i = tid; i < 512; i += 64) { piv[i] = pivr[bt * 512 + i]; cs[i] = i; }
  __syncthreads();
  if (tid == 0) {
    for (int j = 511; j >= 0; j--) { int r = piv[j]; int tp = cs[j]; cs[j] = cs[r]; cs[r] = tp; }
  }
  __syncthreads();
  const float* Mb = M + (size_t)bt * 262144;
  for (int i = tid; i < 512; i += 64) {
    colsrc[bt * 512 + i] = cs[i];
    diagv[bt * 512 + i] = Mb[(size_t)i * 512 + cs[i]];
  }
}

// ---------------------------------------------------------------------------
// 8) Final: att[k,q] = (k!=0)*A[q,k]*diag[k] - (q!=0)*A[q,k]*LLinv[k,q]
//    LLinv[k,q] = M[k][colsrc[q]]. In-place transpose-paired 64x64 tiles in d_out.
// ---------------------------------------------------------------------------
__global__ __launch_bounds__(256) void final_kernel(const float* __restrict__ M,
    const int* __restrict__ colsrc, const float* __restrict__ diagv,
    float* __restrict__ Aout) {
  const int bt = blockIdx.y;
  int x = blockIdx.x, ti = 0;
  while (x >= 8 - ti) { x -= 8 - ti; ti++; }
  const int tj = ti + x;
  const int tid = threadIdx.x, c = tid & 63, g = tid >> 6;
  __shared__ float Aa[64][65];
  __shared__ float Ab[64][65];
  __shared__ int csj[64], csi[64];
  __shared__ float dgi[64], dgj[64];
  const size_t base = (size_t)bt * 262144;
  const float* Mb = M + base;
  float* Ao = Aout + base;
  if (tid < 64)       { csj[tid] = colsrc[bt * 512 + tj * 64 + tid];
                        dgi[tid] = diagv[bt * 512 + ti * 64 + tid]; }
  else if (tid < 128) { int u = tid - 64;
                        csi[u] = colsrc[bt * 512 + ti * 64 + u];
                        dgj[u] = diagv[bt * 512 + tj * 64 + u]; }
  for (int rr = g; rr < 64; rr += 4)
    Aa[rr][c] = Ao[(size_t)(tj * 64 + rr) * 512 + ti * 64 + c];
  if (ti != tj)
    for (int rr = g; rr < 64; rr += 4)
      Ab[rr][c] = Ao[(size_t)(ti * 64 + rr) * 512 + tj * 64 + c];
  __syncthreads();
  for (int kk = g; kk < 64; kk += 4) {               // O1: rows Ti, cols Tj
    int krow = ti * 64 + kk, q = tj * 64 + c;
    float a = Aa[c][kk];
    float llv = Mb[(size_t)krow * 512 + csj[c]];
    float val = 0.f;
    if (krow != 0) val = a * dgi[kk];
    if (q != 0)    val -= a * llv;
    Ao[(size_t)krow * 512 + q] = val;
  }
  if (ti != tj) {
    for (int kk = g; kk < 64; kk += 4) {             // O2: rows Tj, cols Ti
      int krow = tj * 64 + kk, q = ti * 64 + c;
      float a = Ab[c][kk];
      float llv = Mb[(size_t)krow * 512 + csi[c]];
      float val = 0.f;
      if (krow != 0) val = a * dgj[kk];
      if (q != 0)    val -= a * llv;
      Ao[(size_t)krow * 512 + q] = val;
    }
  }
}

// ---------------------------------------------------------------------------
extern "C" void kernel_launch(void* const* d_in, const int* in_sizes, int n_in,
                              void* d_out, int out_size, void* d_ws, size_t ws_size,
                              hipStream_t stream) {
  const float* x     = (const float*)d_in[0];
  const int*   mask  = (const int*)d_in[1];
  const float* Wq    = (const float*)d_in[2];
  const float* bq    = (const float*)d_in[3];
  const float* Wk    = (const float*)d_in[4];
  const float* bk    = (const float*)d_in[5];
  const float* Wroot = (const float*)d_in[6];
  const float* broot = (const float*)d_in[7];
  float* A = (float*)d_out;                    // holds exp(p_attn) then final att

  float* ws = (float*)d_ws;
  size_t off = 0;
  float* M    = ws + off; off += (size_t)256 * 512 * 512;   // 256 MB
  float* Qb   = ws + off; off += (size_t)16384 * 768;       // 50 MB
  float* Kb   = ws + off; off += (size_t)16384 * 768;       // 50 MB
  float* fbuf = ws + off; off += (size_t)256 * 512;
  float* deg  = ws + off; off += (size_t)256 * 512;
  float* dgv  = ws + off; off += (size_t)256 * 512;
  int* pivr   = (int*)(ws + off); off += (size_t)256 * 512;
  int* csrc   = (int*)(ws + off); off += (size_t)256 * 512;
  if (ws_size < off * sizeof(float)) return;   // workspace too small: visible failure

  proj_gemm<<<dim3(128, 12, 2), 256, 0, stream>>>(x, Wq, bq, Wk, bk, Qb, Kb);
  f_kernel<<<64, 256, 0, stream>>>(x, Wroot, broot, fbuf);
  scores_kernel<<<dim3(8192), 256, 0, stream>>>(Qb, Kb, mask, A);
  deg_kernel<<<dim3(2, 256), 256, 0, stream>>>(A, deg);
  build_kernel<<<dim3(512, 256), 128, 0, stream>>>(A, fbuf, deg, M);
  for (int ph = 0; ph < NPH; ph++) {
    panel_kernel<<<256, 512, 0, stream>>>(M, pivr, ph);
    update_kernel<<<dim3(2048), 256, 0, stream>>>(M, pivr, ph);
  }
  colsrc_kernel<<<256, 64, 0, stream>>>(M, pivr, csrc, dgv);
  final_kernel<<<dim3(36, 256), 256, 0, stream>>>(M, csrc, dgv, A);
}

// Round 3
// 8505.099 us; speedup vs baseline: 2.6115x; 2.6115x over previous
//
#include <hip/hip_runtime.h>
#include <math.h>

// Problem constants
#define NB_ 64          // GJ block size (64 halves update-pass M traffic vs 32)
#define NPH 8           // 512 / NB_
// B=32, L=512, H=768, T=8, DK=96, BT=256

// ---------------------------------------------------------------------------
// 1) Q/K projection: out[m][n] = x[m][:] . W[n][:] + bias[n]   (W row-major, "NT")
//    BM=128, BN=64, BK=16, 256 threads, 8x4 micro-tile. grid.z selects Wq/Wk.
//    Thread owns rows {tm*4+i, 64+tm*4+i}: LDS reads at 16B lane spacing
//    (2-way = free) instead of 32B (4-way conflict).
// ---------------------------------------------------------------------------
__global__ __launch_bounds__(256) void proj_gemm(const float* __restrict__ x,
    const float* __restrict__ Wq, const float* __restrict__ bq,
    const float* __restrict__ Wk, const float* __restrict__ bk,
    float* __restrict__ Qb, float* __restrict__ Kb) {
  const float* W    = blockIdx.z ? Wk : Wq;
  const float* bias = blockIdx.z ? bk : bq;
  float* out        = blockIdx.z ? Kb : Qb;
  const int m0 = blockIdx.x * 128;
  const int n0 = blockIdx.y * 64;
  __shared__ float Xs[16][132];   // [k][m], stride 132 keeps f4 alignment + bank spread
  __shared__ float Ws[16][68];    // [k][n]
  const int tid = threadIdx.x;
  const int tm = tid & 15, tn = tid >> 4;   // both [0,16)
  float acc[8][4];
#pragma unroll
  for (int i = 0; i < 8; i++)
#pragma unroll
    for (int j = 0; j < 4; j++) acc[i][j] = 0.f;

  for (int kk = 0; kk < 768; kk += 16) {
    // load X tile 128x16 (512 float4)
#pragma unroll
    for (int rep = 0; rep < 2; rep++) {
      int fidx = tid + rep * 256;
      int row = fidx >> 2, f4i = fidx & 3;
      float4 v = ((const float4*)(x + (size_t)(m0 + row) * 768 + kk))[f4i];
      Xs[f4i * 4 + 0][row] = v.x; Xs[f4i * 4 + 1][row] = v.y;
      Xs[f4i * 4 + 2][row] = v.z; Xs[f4i * 4 + 3][row] = v.w;
    }
    { // load W tile 64x16 (256 float4)
      int row = tid >> 2, f4i = tid & 3;
      float4 v = ((const float4*)(W + (size_t)(n0 + row) * 768 + kk))[f4i];
      Ws[f4i * 4 + 0][row] = v.x; Ws[f4i * 4 + 1][row] = v.y;
      Ws[f4i * 4 + 2][row] = v.z; Ws[f4i * 4 + 3][row] = v.w;
    }
    __syncthreads();
#pragma unroll
    for (int k = 0; k < 16; k++) {
      float4 a0 = *(const float4*)&Xs[k][tm * 4];        // banks 4tm..: 2-way, free
      float4 a1 = *(const float4*)&Xs[k][tm * 4 + 64];   // same pattern
      float4 bv = *(const float4*)&Ws[k][tn * 4];        // wave-uniform broadcast
      float am[8] = {a0.x,a0.y,a0.z,a0.w,a1.x,a1.y,a1.z,a1.w};
      float bn[4] = {bv.x,bv.y,bv.z,bv.w};
#pragma unroll
      for (int i = 0; i < 8; i++)
#pragma unroll
        for (int j = 0; j < 4; j++) acc[i][j] += am[i] * bn[j];
    }
    __syncthreads();
  }
  float b0 = bias[n0 + tn * 4 + 0], b1 = bias[n0 + tn * 4 + 1];
  float b2 = bias[n0 + tn * 4 + 2], b3 = bias[n0 + tn * 4 + 3];
#pragma unroll
  for (int i = 0; i < 4; i++) {
    float4 o = {acc[i][0] + b0, acc[i][1] + b1, acc[i][2] + b2, acc[i][3] + b3};
    *(float4*)(out + (size_t)(m0 + tm * 4 + i) * 768 + n0 + tn * 4) = o;
    float4 o2 = {acc[i+4][0] + b0, acc[i+4][1] + b1, acc[i+4][2] + b2, acc[i+4][3] + b3};
    *(float4*)(out + (size_t)(m0 + 64 + tm * 4 + i) * 768 + n0 + tn * 4) = o2;
  }
}

// ---------------------------------------------------------------------------
// 2) f[b,t,l] = x[b,l,:] . Wroot[t,:] + broot[t]
// ---------------------------------------------------------------------------
__global__ __launch_bounds__(256) void f_kernel(const float* __restrict__ x,
    const float* __restrict__ Wroot, const float* __restrict__ broot,
    float* __restrict__ fout) {
  int row = blockIdx.x * 256 + threadIdx.x;   // b*512+l
  int b = row >> 9, l = row & 511;
  float acc[8] = {0,0,0,0,0,0,0,0};
  const float4* xr = (const float4*)(x + (size_t)row * 768);
  for (int h4 = 0; h4 < 192; h4++) {
    float4 xv = xr[h4];
#pragma unroll
    for (int t = 0; t < 8; t++) {
      float4 wv = ((const float4*)(Wroot + (size_t)t * 768))[h4];
      acc[t] += xv.x * wv.x + xv.y * wv.y + xv.z * wv.z + xv.w * wv.w;
    }
  }
#pragma unroll
  for (int t = 0; t < 8; t++)
    fout[(size_t)((b * 8 + t) << 9) + l] = acc[t] + broot[t];
}

// ---------------------------------------------------------------------------
// 3) scores -> softmax -> A = exp(p)*(1-eye), written to d_out.
//    Register-lean inner loop (acc[16] + one kv float4); XCD-chunked grid.
// ---------------------------------------------------------------------------
__global__ __launch_bounds__(256) void scores_kernel(const float* __restrict__ Qb,
    const float* __restrict__ Kb, const int* __restrict__ mask,
    float* __restrict__ A) {
  const int lin = blockIdx.x;                 // 8192 blocks
  const int xcd = lin & 7;
  const int idx = lin >> 3;                   // 0..1023 within XCD
  const int bt  = xcd * 32 + (idx >> 5);      // 32 bt per XCD, contiguous
  const int q0  = (idx & 31) * 16;
  const int b = bt >> 3, t = bt & 7;
  __shared__ float  S[16][512];
  __shared__ float4 Qs4[16][24];              // Q tile as float4 [q][d4]
  __shared__ float  part[16][16];
  __shared__ float  invsum[16];
  const int tid = threadIdx.x;
  for (int i = tid; i < 384; i += 256) {      // 16*24 float4
    int q = i / 24, f4 = i % 24;
    Qs4[q][f4] =
        ((const float4*)(Qb + (size_t)(b * 512 + q0 + q) * 768 + t * 96))[f4];
  }
  __syncthreads();
  const float scl = 0.10206207261596575f;     // 1/sqrt(96)
#pragma unroll 1
  for (int rep = 0; rep < 2; rep++) {
    const int k = rep * 256 + tid;
    const float4* kr = (const float4*)(Kb + (size_t)(b * 512 + k) * 768 + t * 96);
    float acc[16];
#pragma unroll
    for (int q = 0; q < 16; q++) acc[q] = 0.f;
#pragma unroll 4
    for (int f4 = 0; f4 < 24; f4++) {
      float4 kv = kr[f4];
#pragma unroll
      for (int q = 0; q < 16; q++) {
        float4 qv = Qs4[q][f4];               // wave-uniform -> LDS broadcast
        acc[q] += qv.x * kv.x + qv.y * kv.y + qv.z * kv.z + qv.w * kv.w;
      }
    }
    int mk = mask[b * 512 + k];
#pragma unroll
    for (int q = 0; q < 16; q++)
      S[q][k] = mk ? expf(acc[q] * scl) : 0.f;
  }
  __syncthreads();
  { // row sums; k = j + 16*i keeps lanes on 16 distinct banks (4-way max)
    int q = tid >> 4, j = tid & 15;
    float s = 0.f;
#pragma unroll
    for (int i = 0; i < 32; i++) s += S[q][j + 16 * i];
    part[q][j] = s;
  }
  __syncthreads();
  if (tid < 16) {
    float s = 0.f;
#pragma unroll
    for (int j = 0; j < 16; j++) s += part[tid][j];
    invsum[tid] = 1.f / fmaxf(s, 1e-30f);
  }
  __syncthreads();
#pragma unroll 1
  for (int rep = 0; rep < 2; rep++) {
    const int k = rep * 256 + tid;
#pragma unroll
    for (int q = 0; q < 16; q++) {
      float p = S[q][k] * invsum[q];
      float a = (q0 + q == k) ? 0.f : expf(p);
      A[(size_t)(bt * 512 + q0 + q) * 512 + k] = a;
    }
  }
}

// 4) deg[bt][k] = sum_q A[bt][q][k]
__global__ __launch_bounds__(256) void deg_kernel(const float* __restrict__ A,
                                                  float* __restrict__ deg) {
  int bt = blockIdx.y, k = blockIdx.x * 256 + threadIdx.x;
  const float* Ab = A + (size_t)bt * 262144;
  float s = 0.f;
  for (int q = 0; q < 512; q++) s += Ab[(size_t)q * 512 + k];
  deg[bt * 512 + k] = s;
}

// 5) M = Lbar:  row0 = f ; else -A + deg on diag
__global__ __launch_bounds__(128) void build_kernel(const float* __restrict__ A,
    const float* __restrict__ fin, const float* __restrict__ deg,
    float* __restrict__ M) {
  int q = blockIdx.x, bt = blockIdx.y, tid = threadIdx.x;
  size_t base = (size_t)bt * 262144;
  float4* Mo = (float4*)(M + base + (size_t)q * 512);
  if (q == 0) {
    Mo[tid] = ((const float4*)(fin + (size_t)bt * 512))[tid];
  } else {
    float4 a = ((const float4*)(A + base + (size_t)q * 512))[tid];
    float4 m = {-a.x, -a.y, -a.z, -a.w};
    int k0 = tid * 4;
    if (q >= k0 && q < k0 + 4) {
      float d = deg[bt * 512 + q];
      if      (q == k0    ) m.x += d;
      else if (q == k0 + 1) m.y += d;
      else if (q == k0 + 2) m.z += d;
      else                  m.w += d;
    }
    Mo[tid] = m;
  }
}

// ---------------------------------------------------------------------------
// 6a) Panel factorization: in-place GJ with partial pivoting over 64 pivot
//     columns. 512 threads, ONE row per thread (r[64] = 64 VGPR). Pivot
//     sequence identical to unblocked GJ w/ partial pivoting.
// ---------------------------------------------------------------------------
__global__ __launch_bounds__(512) void panel_kernel(float* __restrict__ M,
                                                    int* __restrict__ pivr, int ph) {
  const int bt = blockIdx.x, tid = threadIdx.x;
  const int j0 = ph * NB_;
  __shared__ float rowj[NB_];
  __shared__ float bufj[NB_], bufr[NB_];
  __shared__ float pivval_s;
  __shared__ unsigned long long wred[8];
  __shared__ int pivlist[NB_];
  float* Mb = M + (size_t)bt * 262144;
  float r[NB_];
  {
    const float4* p0 = (const float4*)(Mb + (size_t)tid * 512 + j0);
#pragma unroll
    for (int fi = 0; fi < 16; fi++) {
      float4 a = p0[fi];
      r[4*fi] = a.x; r[4*fi+1] = a.y; r[4*fi+2] = a.z; r[4*fi+3] = a.w;
    }
  }
  const int lane = tid & 63, wv = tid >> 6;
  for (int l = 0; l < NB_; l++) {
    const int j = j0 + l;
    // extract column-l value of my row (pre-swap)
    float v = 0.f;
#pragma unroll
    for (int c = 0; c < NB_; c++) v = (c == l) ? r[c] : v;
    // pivot search over rows >= j
    float best = -1.f; int bidx = 0;
    if (tid >= j) { best = fabsf(v); bidx = tid; }
    unsigned long long pk = (best >= 0.f)
        ? ((((unsigned long long)__float_as_uint(best)) << 32) | (unsigned)bidx) : 0ull;
#pragma unroll
    for (int off = 32; off > 0; off >>= 1) {
      unsigned long long o = __shfl_xor(pk, off, 64);
      if (o > pk) pk = o;
    }
    if (lane == 0) wred[wv] = pk;
    __syncthreads();
    unsigned long long ma = wred[0];
#pragma unroll
    for (int w = 1; w < 8; w++) ma = (wred[w] > ma) ? wred[w] : ma;
    const int rr = (int)(unsigned)(ma & 0xffffffffull);
    // stage swap rows + pivot value
    if (tid == rr) {
      pivval_s = v;
#pragma unroll
      for (int c = 0; c < NB_; c++) bufr[c] = r[c];
    }
    if (tid == j) {
#pragma unroll
      for (int c = 0; c < NB_; c++) bufj[c] = r[c];
    }
    if (tid == 0) pivlist[l] = rr;
    __syncthreads();
    const float rinv = 1.f / pivval_s;
    if (tid == j) {     // new pivot row = (old row rr)/p, col l -> 1/p
#pragma unroll
      for (int c = 0; c < NB_; c++) {
        float nv = (c == l) ? rinv : bufr[c] * rinv;
        r[c] = nv;
        rowj[c] = nv;
      }
    }
    if (rr != j && tid == rr) {  // row rr <- old row j
#pragma unroll
      for (int c = 0; c < NB_; c++) r[c] = bufj[c];
    }
    __syncthreads();
    // eliminate all rows != j (full GJ update, in-place column rule)
    if (tid != j) {
      float m = 0.f;
#pragma unroll
      for (int c = 0; c < NB_; c++) m = (c == l) ? r[c] : m;
#pragma unroll
      for (int c = 0; c < NB_; c++) r[c] = ((c == l) ? 0.f : r[c]) - m * rowj[c];
    }
    __syncthreads();
  }
  { // write back panel
    float4* p0 = (float4*)(Mb + (size_t)tid * 512 + j0);
#pragma unroll
    for (int fi = 0; fi < 16; fi++) {
      float4 a = {r[4*fi], r[4*fi+1], r[4*fi+2], r[4*fi+3]};
      p0[fi] = a;
    }
  }
  if (tid < NB_) pivr[bt * 512 + j0 + tid] = pivlist[tid];
}

// ---------------------------------------------------------------------------
// 6b) Rest-of-matrix update: X <- X[perm] + (panel - I_block) * X[perm][blockrows]
//     1-D XCD-chunked grid. FULL unroll on the 16-trip FMA loop is mandatory:
//     partial unroll makes xb[] runtime-indexed -> scratch spill (rule #20;
//     round-2 measured 1.3GB of spill reads + 134MB spill writes/dispatch).
// ---------------------------------------------------------------------------
__global__ __launch_bounds__(256) void update_kernel(float* __restrict__ M,
                                                     const int* __restrict__ pivr, int ph) {
  const int lin = blockIdx.x;                 // 2048 blocks
  const int xcd = lin & 7;
  const int idx = lin >> 3;                   // 0..255 within XCD
  const int bt  = xcd * 32 + (idx >> 3);      // 32 bt per XCD
  const int t0  = (idx & 7) * 64;
  const int j0 = ph * NB_;
  __shared__ int perm_s[512];
  __shared__ short rowslot_s[512];
  __shared__ float Xb[NB_][64];
  __shared__ float staged[128][64];           // 64 transpositions touch <=128 rows
  __shared__ int srcrow[128];
  __shared__ int cnt;
  const int tid = threadIdx.x;
  const int c = tid & 63, g = tid >> 6;
  float* Mb = M + (size_t)bt * 262144;
  for (int i = tid; i < 512; i += 256) { perm_s[i] = i; rowslot_s[i] = -1; }
  if (tid == 0) cnt = 0;
  __syncthreads();
  if (tid == 0) {
    for (int l = 0; l < NB_; l++) {
      int r = pivr[bt * 512 + j0 + l];
      int tp = perm_s[j0 + l]; perm_s[j0 + l] = perm_s[r]; perm_s[r] = tp;
    }
  }
  __syncthreads();
  for (int i = tid; i < 512; i += 256) {
    if (perm_s[i] != i) { int s = atomicAdd(&cnt, 1); rowslot_s[i] = (short)s; srcrow[s] = perm_s[i]; }
  }
  __syncthreads();
  const int nmv = cnt;   // <= 128
  for (int s = g; s < nmv; s += 4) staged[s][c] = Mb[(size_t)srcrow[s] * 512 + t0 + c];
  for (int l = g; l < NB_; l += 4) Xb[l][c] = Mb[(size_t)perm_s[j0 + l] * 512 + t0 + c];
  __syncthreads();
  float xb[NB_];
#pragma unroll
  for (int l = 0; l < NB_; l++) xb[l] = Xb[l][c];
  const int col = t0 + c;
  const bool colok = !(col >= j0 && col < j0 + NB_);
  for (int i = g * 128; i < g * 128 + 128; i++) {
    const float4* vp = (const float4*)(Mb + (size_t)i * 512 + j0);
    int rs = rowslot_s[i];
    float s = (rs >= 0) ? staged[rs][c] : Mb[(size_t)i * 512 + col];
#pragma unroll
    for (int fi = 0; fi < 16; fi++) {        // FULL unroll: xb stays in VGPRs
      float4 v = vp[fi];
      s += v.x * xb[4*fi] + v.y * xb[4*fi+1] + v.z * xb[4*fi+2] + v.w * xb[4*fi+3];
    }
    if (i >= j0 && i < j0 + NB_) {     // subtract identity part of V
      int li = i - j0;
      float xs = 0.f;
#pragma unroll
      for (int l = 0; l < NB_; l++) xs = (l == li) ? xb[l] : xs;
      s -= xs;
    }
    if (colok) Mb[(size_t)i * 512 + col] = s;
  }
}

// 7) column unscramble map + diagonal of LLinv
__global__ __launch_bounds__(64) void colsrc_kernel(const float* __restrict__ M,
    const int* __restrict__ pivr, int* __restrict__ colsrc, float* __restrict__ diagv) {
  const int bt = blockIdx.x, tid = threadIdx.x;
  __shared__ int piv[512];
  __shared__ int cs[512];
  for (int i = tid; i < 512; i += 64) { piv[i] = pivr[bt * 512 + i]; cs[i] = i; }
  __syncthreads();
  if (tid == 0) {
    for (int j = 511; j >= 0; j--) { int r = piv[j]; int tp = cs[j]; cs[j] = cs[r]; cs[r] = tp; }
  }
  __syncthreads();
  const float* Mb = M + (size_t)bt * 262144;
  for (int i = tid; i < 512; i += 64) {
    colsrc[bt * 512 + i] = cs[i];
    diagv[bt * 512 + i] = Mb[(size_t)i * 512 + cs[i]];
  }
}

// ---------------------------------------------------------------------------
// 8) Final: att[k,q] = (k!=0)*A[q,k]*diag[k] - (q!=0)*A[q,k]*LLinv[k,q]
//    LLinv[k,q] = M[k][colsrc[q]]. In-place transpose-paired 64x64 tiles in d_out.
// ---------------------------------------------------------------------------
__global__ __launch_bounds__(256) void final_kernel(const float* __restrict__ M,
    const int* __restrict__ colsrc, const float* __restrict__ diagv,
    float* __restrict__ Aout) {
  const int bt = blockIdx.y;
  int x = blockIdx.x, ti = 0;
  while (x >= 8 - ti) { x -= 8 - ti; ti++; }
  const int tj = ti + x;
  const int tid = threadIdx.x, c = tid & 63, g = tid >> 6;
  __shared__ float Aa[64][65];
  __shared__ float Ab[64][65];
  __shared__ int csj[64], csi[64];
  __shared__ float dgi[64], dgj[64];
  const size_t base = (size_t)bt * 262144;
  const float* Mb = M + base;
  float* Ao = Aout + base;
  if (tid < 64)       { csj[tid] = colsrc[bt * 512 + tj * 64 + tid];
                        dgi[tid] = diagv[bt * 512 + ti * 64 + tid]; }
  else if (tid < 128) { int u = tid - 64;
                        csi[u] = colsrc[bt * 512 + ti * 64 + u];
                        dgj[u] = diagv[bt * 512 + tj * 64 + u]; }
  for (int rr = g; rr < 64; rr += 4)
    Aa[rr][c] = Ao[(size_t)(tj * 64 + rr) * 512 + ti * 64 + c];
  if (ti != tj)
    for (int rr = g; rr < 64; rr += 4)
      Ab[rr][c] = Ao[(size_t)(ti * 64 + rr) * 512 + tj * 64 + c];
  __syncthreads();
  for (int kk = g; kk < 64; kk += 4) {               // O1: rows Ti, cols Tj
    int krow = ti * 64 + kk, q = tj * 64 + c;
    float a = Aa[c][kk];
    float llv = Mb[(size_t)krow * 512 + csj[c]];
    float val = 0.f;
    if (krow != 0) val = a * dgi[kk];
    if (q != 0)    val -= a * llv;
    Ao[(size_t)krow * 512 + q] = val;
  }
  if (ti != tj) {
    for (int kk = g; kk < 64; kk += 4) {             // O2: rows Tj, cols Ti
      int krow = tj * 64 + kk, q = ti * 64 + c;
      float a = Ab[c][kk];
      float llv = Mb[(size_t)krow * 512 + csi[c]];
      float val = 0.f;
      if (krow != 0) val = a * dgj[kk];
      if (q != 0)    val -= a * llv;
      Ao[(size_t)krow * 512 + q] = val;
    }
  }
}

// ---------------------------------------------------------------------------
extern "C" void kernel_launch(void* const* d_in, const int* in_sizes, int n_in,
                              void* d_out, int out_size, void* d_ws, size_t ws_size,
                              hipStream_t stream) {
  const float* x     = (const float*)d_in[0];
  const int*   mask  = (const int*)d_in[1];
  const float* Wq    = (const float*)d_in[2];
  const float* bq    = (const float*)d_in[3];
  const float* Wk    = (const float*)d_in[4];
  const float* bk    = (const float*)d_in[5];
  const float* Wroot = (const float*)d_in[6];
  const float* broot = (const float*)d_in[7];
  float* A = (float*)d_out;                    // holds exp(p_attn) then final att

  float* ws = (float*)d_ws;
  size_t off = 0;
  float* M    = ws + off; off += (size_t)256 * 512 * 512;   // 256 MB
  float* Qb   = ws + off; off += (size_t)16384 * 768;       // 50 MB
  float* Kb   = ws + off; off += (size_t)16384 * 768;       // 50 MB
  float* fbuf = ws + off; off += (size_t)256 * 512;
  float* deg  = ws + off; off += (size_t)256 * 512;
  float* dgv  = ws + off; off += (size_t)256 * 512;
  int* pivr   = (int*)(ws + off); off += (size_t)256 * 512;
  int* csrc   = (int*)(ws + off); off += (size_t)256 * 512;
  if (ws_size < off * sizeof(float)) return;   // workspace too small: visible failure

  proj_gemm<<<dim3(128, 12, 2), 256, 0, stream>>>(x, Wq, bq, Wk, bk, Qb, Kb);
  f_kernel<<<64, 256, 0, stream>>>(x, Wroot, broot, fbuf);
  scores_kernel<<<dim3(8192), 256, 0, stream>>>(Qb, Kb, mask, A);
  deg_kernel<<<dim3(2, 256), 256, 0, stream>>>(A, deg);
  build_kernel<<<dim3(512, 256), 128, 0, stream>>>(A, fbuf, deg, M);
  for (int ph = 0; ph < NPH; ph++) {
    panel_kernel<<<256, 512, 0, stream>>>(M, pivr, ph);
    update_kernel<<<dim3(2048), 256, 0, stream>>>(M, pivr, ph);
  }
  colsrc_kernel<<<256, 64, 0, stream>>>(M, pivr, csrc, dgv);
  final_kernel<<<dim3(36, 256), 256, 0, stream>>>(M, csrc, dgv, A);
}

// Round 4
// 4535.593 us; speedup vs baseline: 4.8970x; 1.8752x over previous
//
#include <hip/hip_runtime.h>
#include <math.h>

// Problem constants
#define NB_ 64          // GJ block size
#define NPH 8           // 512 / NB_
// B=32, L=512, H=768, T=8, DK=96, BT=256

// ---------------------------------------------------------------------------
// 1) Q/K projection: out[m][n] = x[m][:] . W[n][:] + bias[n]   (W row-major, "NT")
//    BM=128, BN=64, BK=16, 256 threads, 8x4 micro-tile. grid.z selects Wq/Wk.
// ---------------------------------------------------------------------------
__global__ __launch_bounds__(256) void proj_gemm(const float* __restrict__ x,
    const float* __restrict__ Wq, const float* __restrict__ bq,
    const float* __restrict__ Wk, const float* __restrict__ bk,
    float* __restrict__ Qb, float* __restrict__ Kb) {
  const float* W    = blockIdx.z ? Wk : Wq;
  const float* bias = blockIdx.z ? bk : bq;
  float* out        = blockIdx.z ? Kb : Qb;
  const int m0 = blockIdx.x * 128;
  const int n0 = blockIdx.y * 64;
  __shared__ float Xs[16][132];   // [k][m]
  __shared__ float Ws[16][68];    // [k][n]
  const int tid = threadIdx.x;
  const int tm = tid & 15, tn = tid >> 4;   // both [0,16)
  float acc[8][4];
#pragma unroll
  for (int i = 0; i < 8; i++)
#pragma unroll
    for (int j = 0; j < 4; j++) acc[i][j] = 0.f;

  for (int kk = 0; kk < 768; kk += 16) {
#pragma unroll
    for (int rep = 0; rep < 2; rep++) {
      int fidx = tid + rep * 256;
      int row = fidx >> 2, f4i = fidx & 3;
      float4 v = ((const float4*)(x + (size_t)(m0 + row) * 768 + kk))[f4i];
      Xs[f4i * 4 + 0][row] = v.x; Xs[f4i * 4 + 1][row] = v.y;
      Xs[f4i * 4 + 2][row] = v.z; Xs[f4i * 4 + 3][row] = v.w;
    }
    { int row = tid >> 2, f4i = tid & 3;
      float4 v = ((const float4*)(W + (size_t)(n0 + row) * 768 + kk))[f4i];
      Ws[f4i * 4 + 0][row] = v.x; Ws[f4i * 4 + 1][row] = v.y;
      Ws[f4i * 4 + 2][row] = v.z; Ws[f4i * 4 + 3][row] = v.w;
    }
    __syncthreads();
#pragma unroll
    for (int k = 0; k < 16; k++) {
      float4 a0 = *(const float4*)&Xs[k][tm * 4];        // 2-way, free
      float4 a1 = *(const float4*)&Xs[k][tm * 4 + 64];
      float4 bv = *(const float4*)&Ws[k][tn * 4];
      float am[8] = {a0.x,a0.y,a0.z,a0.w,a1.x,a1.y,a1.z,a1.w};
      float bn[4] = {bv.x,bv.y,bv.z,bv.w};
#pragma unroll
      for (int i = 0; i < 8; i++)
#pragma unroll
        for (int j = 0; j < 4; j++) acc[i][j] += am[i] * bn[j];
    }
    __syncthreads();
  }
  float b0 = bias[n0 + tn * 4 + 0], b1 = bias[n0 + tn * 4 + 1];
  float b2 = bias[n0 + tn * 4 + 2], b3 = bias[n0 + tn * 4 + 3];
#pragma unroll
  for (int i = 0; i < 4; i++) {
    float4 o = {acc[i][0] + b0, acc[i][1] + b1, acc[i][2] + b2, acc[i][3] + b3};
    *(float4*)(out + (size_t)(m0 + tm * 4 + i) * 768 + n0 + tn * 4) = o;
    float4 o2 = {acc[i+4][0] + b0, acc[i+4][1] + b1, acc[i+4][2] + b2, acc[i+4][3] + b3};
    *(float4*)(out + (size_t)(m0 + 64 + tm * 4 + i) * 768 + n0 + tn * 4) = o2;
  }
}

// ---------------------------------------------------------------------------
// 2) f[b,t,l] = x[b,l,:] . Wroot[t,:] + broot[t]
// ---------------------------------------------------------------------------
__global__ __launch_bounds__(256) void f_kernel(const float* __restrict__ x,
    const float* __restrict__ Wroot, const float* __restrict__ broot,
    float* __restrict__ fout) {
  int row = blockIdx.x * 256 + threadIdx.x;   // b*512+l
  int b = row >> 9, l = row & 511;
  float acc[8] = {0,0,0,0,0,0,0,0};
  const float4* xr = (const float4*)(x + (size_t)row * 768);
  for (int h4 = 0; h4 < 192; h4++) {
    float4 xv = xr[h4];
#pragma unroll
    for (int t = 0; t < 8; t++) {
      float4 wv = ((const float4*)(Wroot + (size_t)t * 768))[h4];
      acc[t] += xv.x * wv.x + xv.y * wv.y + xv.z * wv.z + xv.w * wv.w;
    }
  }
#pragma unroll
  for (int t = 0; t < 8; t++)
    fout[(size_t)((b * 8 + t) << 9) + l] = acc[t] + broot[t];
}

// ---------------------------------------------------------------------------
// 3) scores -> softmax -> A = exp(p)*(1-eye). Register-lean; XCD-chunked.
// ---------------------------------------------------------------------------
__global__ __launch_bounds__(256) void scores_kernel(const float* __restrict__ Qb,
    const float* __restrict__ Kb, const int* __restrict__ mask,
    float* __restrict__ A) {
  const int lin = blockIdx.x;                 // 8192 blocks
  const int xcd = lin & 7;
  const int idx = lin >> 3;
  const int bt  = xcd * 32 + (idx >> 5);
  const int q0  = (idx & 31) * 16;
  const int b = bt >> 3, t = bt & 7;
  __shared__ float  S[16][512];
  __shared__ float4 Qs4[16][24];
  __shared__ float  part[16][16];
  __shared__ float  invsum[16];
  const int tid = threadIdx.x;
  for (int i = tid; i < 384; i += 256) {
    int q = i / 24, f4 = i % 24;
    Qs4[q][f4] =
        ((const float4*)(Qb + (size_t)(b * 512 + q0 + q) * 768 + t * 96))[f4];
  }
  __syncthreads();
  const float scl = 0.10206207261596575f;     // 1/sqrt(96)
#pragma unroll 1
  for (int rep = 0; rep < 2; rep++) {
    const int k = rep * 256 + tid;
    const float4* kr = (const float4*)(Kb + (size_t)(b * 512 + k) * 768 + t * 96);
    float acc[16];
#pragma unroll
    for (int q = 0; q < 16; q++) acc[q] = 0.f;
#pragma unroll 4
    for (int f4 = 0; f4 < 24; f4++) {
      float4 kv = kr[f4];
#pragma unroll
      for (int q = 0; q < 16; q++) {
        float4 qv = Qs4[q][f4];
        acc[q] += qv.x * kv.x + qv.y * kv.y + qv.z * kv.z + qv.w * kv.w;
      }
    }
    int mk = mask[b * 512 + k];
#pragma unroll
    for (int q = 0; q < 16; q++)
      S[q][k] = mk ? expf(acc[q] * scl) : 0.f;
  }
  __syncthreads();
  { int q = tid >> 4, j = tid & 15;
    float s = 0.f;
#pragma unroll
    for (int i = 0; i < 32; i++) s += S[q][j + 16 * i];
    part[q][j] = s; }
  __syncthreads();
  if (tid < 16) {
    float s = 0.f;
#pragma unroll
    for (int j = 0; j < 16; j++) s += part[tid][j];
    invsum[tid] = 1.f / fmaxf(s, 1e-30f);
  }
  __syncthreads();
#pragma unroll 1
  for (int rep = 0; rep < 2; rep++) {
    const int k = rep * 256 + tid;
#pragma unroll
    for (int q = 0; q < 16; q++) {
      float p = S[q][k] * invsum[q];
      float a = (q0 + q == k) ? 0.f : expf(p);
      A[(size_t)(bt * 512 + q0 + q) * 512 + k] = a;
    }
  }
}

// 4) deg[bt][k] = sum_q A[bt][q][k]
__global__ __launch_bounds__(256) void deg_kernel(const float* __restrict__ A,
                                                  float* __restrict__ deg) {
  int bt = blockIdx.y, k = blockIdx.x * 256 + threadIdx.x;
  const float* Ab = A + (size_t)bt * 262144;
  float s = 0.f;
  for (int q = 0; q < 512; q++) s += Ab[(size_t)q * 512 + k];
  deg[bt * 512 + k] = s;
}

// 5) M = Lbar:  row0 = f ; else -A + deg on diag
__global__ __launch_bounds__(128) void build_kernel(const float* __restrict__ A,
    const float* __restrict__ fin, const float* __restrict__ deg,
    float* __restrict__ M) {
  int q = blockIdx.x, bt = blockIdx.y, tid = threadIdx.x;
  size_t base = (size_t)bt * 262144;
  float4* Mo = (float4*)(M + base + (size_t)q * 512);
  if (q == 0) {
    Mo[tid] = ((const float4*)(fin + (size_t)bt * 512))[tid];
  } else {
    float4 a = ((const float4*)(A + base + (size_t)q * 512))[tid];
    float4 m = {-a.x, -a.y, -a.z, -a.w};
    int k0 = tid * 4;
    if (q >= k0 && q < k0 + 4) {
      float d = deg[bt * 512 + q];
      if      (q == k0    ) m.x += d;
      else if (q == k0 + 1) m.y += d;
      else if (q == k0 + 2) m.z += d;
      else                  m.w += d;
    }
    Mo[tid] = m;
  }
}

// ---------------------------------------------------------------------------
// 6a) Panel factorization: in-place GJ with partial pivoting over 64 pivot
//     columns. 512 threads, ONE row per thread (r[64] in VGPRs).
// ---------------------------------------------------------------------------
__global__ __launch_bounds__(512) void panel_kernel(float* __restrict__ M,
                                                    int* __restrict__ pivr, int ph) {
  const int bt = blockIdx.x, tid = threadIdx.x;
  const int j0 = ph * NB_;
  __shared__ float rowj[NB_];
  __shared__ float bufj[NB_], bufr[NB_];
  __shared__ float pivval_s;
  __shared__ unsigned long long wred[8];
  __shared__ int pivlist[NB_];
  float* Mb = M + (size_t)bt * 262144;
  float r[NB_];
  {
    const float4* p0 = (const float4*)(Mb + (size_t)tid * 512 + j0);
#pragma unroll
    for (int fi = 0; fi < 16; fi++) {
      float4 a = p0[fi];
      r[4*fi] = a.x; r[4*fi+1] = a.y; r[4*fi+2] = a.z; r[4*fi+3] = a.w;
    }
  }
  const int lane = tid & 63, wv = tid >> 6;
  for (int l = 0; l < NB_; l++) {
    const int j = j0 + l;
    float v = 0.f;
#pragma unroll
    for (int c = 0; c < NB_; c++) v = (c == l) ? r[c] : v;
    float best = -1.f; int bidx = 0;
    if (tid >= j) { best = fabsf(v); bidx = tid; }
    unsigned long long pk = (best >= 0.f)
        ? ((((unsigned long long)__float_as_uint(best)) << 32) | (unsigned)bidx) : 0ull;
#pragma unroll
    for (int off = 32; off > 0; off >>= 1) {
      unsigned long long o = __shfl_xor(pk, off, 64);
      if (o > pk) pk = o;
    }
    if (lane == 0) wred[wv] = pk;
    __syncthreads();
    unsigned long long ma = wred[0];
#pragma unroll
    for (int w = 1; w < 8; w++) ma = (wred[w] > ma) ? wred[w] : ma;
    const int rr = (int)(unsigned)(ma & 0xffffffffull);
    if (tid == rr) {
      pivval_s = v;
#pragma unroll
      for (int c = 0; c < NB_; c++) bufr[c] = r[c];
    }
    if (tid == j) {
#pragma unroll
      for (int c = 0; c < NB_; c++) bufj[c] = r[c];
    }
    if (tid == 0) pivlist[l] = rr;
    __syncthreads();
    const float rinv = 1.f / pivval_s;
    if (tid == j) {
#pragma unroll
      for (int c = 0; c < NB_; c++) {
        float nv = (c == l) ? rinv : bufr[c] * rinv;
        r[c] = nv;
        rowj[c] = nv;
      }
    }
    if (rr != j && tid == rr) {
#pragma unroll
      for (int c = 0; c < NB_; c++) r[c] = bufj[c];
    }
    __syncthreads();
    if (tid != j) {
      float m = 0.f;
#pragma unroll
      for (int c = 0; c < NB_; c++) m = (c == l) ? r[c] : m;
#pragma unroll
      for (int c = 0; c < NB_; c++) r[c] = ((c == l) ? 0.f : r[c]) - m * rowj[c];
    }
    __syncthreads();
  }
  {
    float4* p0 = (float4*)(Mb + (size_t)tid * 512 + j0);
#pragma unroll
    for (int fi = 0; fi < 16; fi++) {
      float4 a = {r[4*fi], r[4*fi+1], r[4*fi+2], r[4*fi+3]};
      p0[fi] = a;
    }
  }
  if (tid < NB_) pivr[bt * 512 + j0 + tid] = pivlist[tid];
}

// ---------------------------------------------------------------------------
// 6b-pre) Stage: snapshot X rows (64 pivot-source rows) and moved rows into
//     Stg (aliases dead Qb/Kb). Writes rowslot map. Enables row-tiled GEMM
//     update without read-after-write races.
//     Stg layout per bt: rows [0,64) = X rows; rows [64,64+nmv) = moved rows.
// ---------------------------------------------------------------------------
__global__ __launch_bounds__(256) void stage_kernel(const float* __restrict__ M,
    const int* __restrict__ pivr, float* __restrict__ Stg,
    int* __restrict__ rowslot, int ph) {
  const int bt = blockIdx.x, tid = threadIdx.x;
  const int j0 = ph * NB_;
  __shared__ int perm_s[512];
  __shared__ int srcrow[128];
  __shared__ int cnt;
  const float* Mb = M + (size_t)bt * 262144;
  float* Sb = Stg + (size_t)bt * 98304;       // 192*512 floats per bt
  int* rsb = rowslot + bt * 512;
  for (int i = tid; i < 512; i += 256) perm_s[i] = i;
  if (tid == 0) cnt = 0;
  __syncthreads();
  if (tid == 0) {
    for (int l = 0; l < NB_; l++) {
      int r = pivr[bt * 512 + j0 + l];
      int tp = perm_s[j0 + l]; perm_s[j0 + l] = perm_s[r]; perm_s[r] = tp;
    }
  }
  __syncthreads();
  for (int i = tid; i < 512; i += 256) {
    int s = -1;
    if (perm_s[i] != i) { s = atomicAdd(&cnt, 1); srcrow[s] = perm_s[i]; }
    rsb[i] = s;
  }
  __syncthreads();
  const int nmv = cnt;   // <= 128
  // X rows: Sb[l][:] = M[perm[j0+l]][:]
  for (int idx = tid; idx < 64 * 128; idx += 256) {
    int l = idx >> 7, f4 = idx & 127;
    ((float4*)(Sb + (size_t)l * 512))[f4] =
        ((const float4*)(Mb + (size_t)perm_s[j0 + l] * 512))[f4];
  }
  // moved rows: Sb[64+s][:] = M[srcrow[s]][:]
  for (int idx = tid; idx < nmv * 128; idx += 256) {
    int s = idx >> 7, f4 = idx & 127;
    ((float4*)(Sb + (size_t)(64 + s) * 512))[f4] =
        ((const float4*)(Mb + (size_t)srcrow[s] * 512))[f4];
  }
}

// ---------------------------------------------------------------------------
// 6b) Rest-of-matrix update as a tiled GEMM (proj_gemm structure):
//     M[i][c] = old(i,c) + V(128xK=64, LDS-chunked) . X(K=64 x 64, LDS-chunked)
//               - [i in pivot block] * X[i-j0][c]
//     old(i,c) = moved ? Stg[64+slot][c] : M[i][c];  X rows from Stg[0..64).
//     Grid: 256 bt * 4 row-tiles * 7 col-tiles (panel col-tile skipped).
// ---------------------------------------------------------------------------
__global__ __launch_bounds__(256) void update_kernel(float* __restrict__ M,
    const float* __restrict__ Stg, const int* __restrict__ rowslot, int ph) {
  const int lin = blockIdx.x;                 // 7168 blocks
  const int xcd = lin & 7;
  const int idx = lin >> 3;                   // 0..895
  const int bt  = xcd * 32 + (idx / 28);
  const int tl  = idx % 28;
  const int rt  = tl / 7;                     // row-tile 0..3
  int ct = tl % 7;                            // col-tile, skip panel tile
  ct += (ct >= ph) ? 1 : 0;
  const int i0 = rt * 128, c0 = ct * 64;
  const int j0 = ph * NB_;
  float* Mb = M + (size_t)bt * 262144;
  const float* Sb = Stg + (size_t)bt * 98304;
  __shared__ float Vs[16][132];
  __shared__ float Xs[16][68];
  __shared__ int rs_s[128];
  const int tid = threadIdx.x;
  const int tm = tid & 15, tn = tid >> 4;
  if (tid < 128) rs_s[tid] = rowslot[bt * 512 + i0 + tid];
  float acc[8][4];
#pragma unroll
  for (int i = 0; i < 8; i++)
#pragma unroll
    for (int j = 0; j < 4; j++) acc[i][j] = 0.f;

#pragma unroll 1
  for (int kk = 0; kk < 64; kk += 16) {
#pragma unroll
    for (int rep = 0; rep < 2; rep++) {       // V chunk: 128 rows x 16 K
      int fidx = tid + rep * 256;
      int row = fidx >> 2, f4i = fidx & 3;
      float4 v = *(const float4*)(Mb + (size_t)(i0 + row) * 512 + j0 + kk + f4i * 4);
      Vs[f4i * 4 + 0][row] = v.x; Vs[f4i * 4 + 1][row] = v.y;
      Vs[f4i * 4 + 2][row] = v.z; Vs[f4i * 4 + 3][row] = v.w;
    }
    {                                          // X chunk: 16 K-rows x 64 cols
      int row = tid >> 4, f4i = tid & 15;
      float4 v = *(const float4*)(Sb + (size_t)(kk + row) * 512 + c0 + f4i * 4);
      *(float4*)&Xs[row][f4i * 4] = v;
    }
    __syncthreads();
#pragma unroll
    for (int k = 0; k < 16; k++) {
      float4 a0 = *(const float4*)&Vs[k][tm * 4];
      float4 a1 = *(const float4*)&Vs[k][tm * 4 + 64];
      float4 bv = *(const float4*)&Xs[k][tn * 4];
      float am[8] = {a0.x,a0.y,a0.z,a0.w,a1.x,a1.y,a1.z,a1.w};
      float bn[4] = {bv.x,bv.y,bv.z,bv.w};
#pragma unroll
      for (int i = 0; i < 8; i++)
#pragma unroll
        for (int j = 0; j < 4; j++) acc[i][j] += am[i] * bn[j];
    }
    __syncthreads();
  }
  const int colg = c0 + tn * 4;
#pragma unroll
  for (int half = 0; half < 2; half++)
#pragma unroll
    for (int i = 0; i < 4; i++) {
      const int rl = half * 64 + tm * 4 + i;
      const int row = i0 + rl;
      const int rs = rs_s[rl];
      const float* oldp = (rs >= 0) ? (Sb + (size_t)(64 + rs) * 512 + colg)
                                    : (Mb + (size_t)row * 512 + colg);
      float4 o = *(const float4*)oldp;
      o.x += acc[half*4+i][0]; o.y += acc[half*4+i][1];
      o.z += acc[half*4+i][2]; o.w += acc[half*4+i][3];
      if (row >= j0 && row < j0 + NB_) {
        float4 xr = *(const float4*)(Sb + (size_t)(row - j0) * 512 + colg);
        o.x -= xr.x; o.y -= xr.y; o.z -= xr.z; o.w -= xr.w;
      }
      *(float4*)(Mb + (size_t)row * 512 + colg) = o;
    }
}

// 7) column unscramble map + diagonal of LLinv
__global__ __launch_bounds__(64) void colsrc_kernel(const float* __restrict__ M,
    const int* __restrict__ pivr, int* __restrict__ colsrc, float* __restrict__ diagv) {
  const int bt = blockIdx.x, tid = threadIdx.x;
  __shared__ int piv[512];
  __shared__ int cs[512];
  for (int i = tid; i < 512; i += 64) { piv[i] = pivr[bt * 512 + i]; cs[i] = i; }
  __syncthreads();
  if (tid == 0) {
    for (int j = 511; j >= 0; j--) { int r = piv[j]; int tp = cs[j]; cs[j] = cs[r]; cs[r] = tp; }
  }
  __syncthreads();
  const float* Mb = M + (size_t)bt * 262144;
  for (int i = tid; i < 512; i += 64) {
    colsrc[bt * 512 + i] = cs[i];
    diagv[bt * 512 + i] = Mb[(size_t)i * 512 + cs[i]];
  }
}

// ---------------------------------------------------------------------------
// 8) Final: att[k,q] = (k!=0)*A[q,k]*diag[k] - (q!=0)*A[q,k]*LLinv[k,q]
// ---------------------------------------------------------------------------
__global__ __launch_bounds__(256) void final_kernel(const float* __restrict__ M,
    const int* __restrict__ colsrc, const float* __restrict__ diagv,
    float* __restrict__ Aout) {
  const int bt = blockIdx.y;
  int x = blockIdx.x, ti = 0;
  while (x >= 8 - ti) { x -= 8 - ti; ti++; }
  const int tj = ti + x;
  const int tid = threadIdx.x, c = tid & 63, g = tid >> 6;
  __shared__ float Aa[64][65];
  __shared__ float Ab[64][65];
  __shared__ int csj[64], csi[64];
  __shared__ float dgi[64], dgj[64];
  const size_t base = (size_t)bt * 262144;
  const float* Mb = M + base;
  float* Ao = Aout + base;
  if (tid < 64)       { csj[tid] = colsrc[bt * 512 + tj * 64 + tid];
                        dgi[tid] = diagv[bt * 512 + ti * 64 + tid]; }
  else if (tid < 128) { int u = tid - 64;
                        csi[u] = colsrc[bt * 512 + ti * 64 + u];
                        dgj[u] = diagv[bt * 512 + tj * 64 + u]; }
  for (int rr = g; rr < 64; rr += 4)
    Aa[rr][c] = Ao[(size_t)(tj * 64 + rr) * 512 + ti * 64 + c];
  if (ti != tj)
    for (int rr = g; rr < 64; rr += 4)
      Ab[rr][c] = Ao[(size_t)(ti * 64 + rr) * 512 + tj * 64 + c];
  __syncthreads();
  for (int kk = g; kk < 64; kk += 4) {               // O1: rows Ti, cols Tj
    int krow = ti * 64 + kk, q = tj * 64 + c;
    float a = Aa[c][kk];
    float llv = Mb[(size_t)krow * 512 + csj[c]];
    float val = 0.f;
    if (krow != 0) val = a * dgi[kk];
    if (q != 0)    val -= a * llv;
    Ao[(size_t)krow * 512 + q] = val;
  }
  if (ti != tj) {
    for (int kk = g; kk < 64; kk += 4) {             // O2: rows Tj, cols Ti
      int krow = tj * 64 + kk, q = ti * 64 + c;
      float a = Ab[c][kk];
      float llv = Mb[(size_t)krow * 512 + csi[c]];
      float val = 0.f;
      if (krow != 0) val = a * dgj[kk];
      if (q != 0)    val -= a * llv;
      Ao[(size_t)krow * 512 + q] = val;
    }
  }
}

// ---------------------------------------------------------------------------
extern "C" void kernel_launch(void* const* d_in, const int* in_sizes, int n_in,
                              void* d_out, int out_size, void* d_ws, size_t ws_size,
                              hipStream_t stream) {
  const float* x     = (const float*)d_in[0];
  const int*   mask  = (const int*)d_in[1];
  const float* Wq    = (const float*)d_in[2];
  const float* bq    = (const float*)d_in[3];
  const float* Wk    = (const float*)d_in[4];
  const float* bk    = (const float*)d_in[5];
  const float* Wroot = (const float*)d_in[6];
  const float* broot = (const float*)d_in[7];
  float* A = (float*)d_out;                    // holds exp(p_attn) then final att

  float* ws = (float*)d_ws;
  size_t off = 0;
  float* M    = ws + off; off += (size_t)256 * 512 * 512;   // 256 MB
  float* Qb   = ws + off; off += (size_t)16384 * 768;       // 50 MB
  float* Kb   = ws + off; off += (size_t)16384 * 768;       // 50 MB
  float* fbuf = ws + off; off += (size_t)256 * 512;
  float* deg  = ws + off; off += (size_t)256 * 512;
  float* dgv  = ws + off; off += (size_t)256 * 512;
  int* pivr   = (int*)(ws + off); off += (size_t)256 * 512;
  int* csrc   = (int*)(ws + off); off += (size_t)256 * 512;
  int* rslot  = (int*)(ws + off); off += (size_t)256 * 512;
  if (ws_size < off * sizeof(float)) return;   // workspace too small: visible failure

  // Stage buffer (192 rows x 512 cols x 256 bt = 100 MB) aliases Qb+Kb,
  // which are dead after scores_kernel.
  float* Stg = Qb;

  proj_gemm<<<dim3(128, 12, 2), 256, 0, stream>>>(x, Wq, bq, Wk, bk, Qb, Kb);
  f_kernel<<<64, 256, 0, stream>>>(x, Wroot, broot, fbuf);
  scores_kernel<<<dim3(8192), 256, 0, stream>>>(Qb, Kb, mask, A);
  deg_kernel<<<dim3(2, 256), 256, 0, stream>>>(A, deg);
  build_kernel<<<dim3(512, 256), 128, 0, stream>>>(A, fbuf, deg, M);
  for (int ph = 0; ph < NPH; ph++) {
    panel_kernel<<<256, 512, 0, stream>>>(M, pivr, ph);
    stage_kernel<<<256, 256, 0, stream>>>(M, pivr, Stg, rslot, ph);
    update_kernel<<<dim3(7168), 256, 0, stream>>>(M, Stg, rslot, ph);
  }
  colsrc_kernel<<<256, 64, 0, stream>>>(M, pivr, csrc, dgv);
  final_kernel<<<dim3(36, 256), 256, 0, stream>>>(M, csrc, dgv, A);
}

// Round 5
// 4478.443 us; speedup vs baseline: 4.9595x; 1.0128x over previous
//
#include <hip/hip_runtime.h>
#include <math.h>

// Problem constants
#define NB_ 64          // GJ block size
#define NPH 8           // 512 / NB_
// B=32, L=512, H=768, T=8, DK=96, BT=256

// ---------------------------------------------------------------------------
// 1) Q/K projection: out[m][n] = x[m][:] . W[n][:] + bias[n]   (W row-major, "NT")
//    BM=128, BN=128, BK=16, 256 threads, 8x8 micro-tile (64 FMA : 4 ds_read).
//    grid.z selects Wq/Wk.
// ---------------------------------------------------------------------------
__global__ __launch_bounds__(256) void proj_gemm(const float* __restrict__ x,
    const float* __restrict__ Wq, const float* __restrict__ bq,
    const float* __restrict__ Wk, const float* __restrict__ bk,
    float* __restrict__ Qb, float* __restrict__ Kb) {
  const float* W    = blockIdx.z ? Wk : Wq;
  const float* bias = blockIdx.z ? bk : bq;
  float* out        = blockIdx.z ? Kb : Qb;
  const int m0 = blockIdx.x * 128;
  const int n0 = blockIdx.y * 128;
  __shared__ float Xs[16][132];   // [k][m]
  __shared__ float Ws2[16][132];  // [k][n]
  const int tid = threadIdx.x;
  const int tm = tid & 15, tn = tid >> 4;   // both [0,16)
  float acc[8][8];
#pragma unroll
  for (int i = 0; i < 8; i++)
#pragma unroll
    for (int j = 0; j < 8; j++) acc[i][j] = 0.f;

  for (int kk = 0; kk < 768; kk += 16) {
#pragma unroll
    for (int rep = 0; rep < 2; rep++) {       // X tile 128x16 (512 f4)
      int fidx = tid + rep * 256;
      int row = fidx >> 2, f4i = fidx & 3;
      float4 v = ((const float4*)(x + (size_t)(m0 + row) * 768 + kk))[f4i];
      Xs[f4i * 4 + 0][row] = v.x; Xs[f4i * 4 + 1][row] = v.y;
      Xs[f4i * 4 + 2][row] = v.z; Xs[f4i * 4 + 3][row] = v.w;
    }
#pragma unroll
    for (int rep = 0; rep < 2; rep++) {       // W tile 128x16 (512 f4)
      int fidx = tid + rep * 256;
      int row = fidx >> 2, f4i = fidx & 3;
      float4 v = ((const float4*)(W + (size_t)(n0 + row) * 768 + kk))[f4i];
      Ws2[f4i * 4 + 0][row] = v.x; Ws2[f4i * 4 + 1][row] = v.y;
      Ws2[f4i * 4 + 2][row] = v.z; Ws2[f4i * 4 + 3][row] = v.w;
    }
    __syncthreads();
#pragma unroll
    for (int k = 0; k < 16; k++) {
      float4 a0 = *(const float4*)&Xs[k][tm * 4];        // 2-way, free
      float4 a1 = *(const float4*)&Xs[k][tm * 4 + 64];
      float4 b0 = *(const float4*)&Ws2[k][tn * 4];       // 4-addr broadcast, free
      float4 b1 = *(const float4*)&Ws2[k][tn * 4 + 64];
      float am[8] = {a0.x,a0.y,a0.z,a0.w,a1.x,a1.y,a1.z,a1.w};
      float bn[8] = {b0.x,b0.y,b0.z,b0.w,b1.x,b1.y,b1.z,b1.w};
#pragma unroll
      for (int i = 0; i < 8; i++)
#pragma unroll
        for (int j = 0; j < 8; j++) acc[i][j] += am[i] * bn[j];
    }
    __syncthreads();
  }
  float bA[4], bB[4];
#pragma unroll
  for (int j = 0; j < 4; j++) {
    bA[j] = bias[n0 + tn * 4 + j];
    bB[j] = bias[n0 + 64 + tn * 4 + j];
  }
#pragma unroll
  for (int half = 0; half < 2; half++)
#pragma unroll
    for (int i = 0; i < 4; i++) {
      const int row = m0 + half * 64 + tm * 4 + i;
      float4 oA = {acc[half*4+i][0] + bA[0], acc[half*4+i][1] + bA[1],
                   acc[half*4+i][2] + bA[2], acc[half*4+i][3] + bA[3]};
      *(float4*)(out + (size_t)row * 768 + n0 + tn * 4) = oA;
      float4 oB = {acc[half*4+i][4] + bB[0], acc[half*4+i][5] + bB[1],
                   acc[half*4+i][6] + bB[2], acc[half*4+i][7] + bB[3]};
      *(float4*)(out + (size_t)row * 768 + n0 + 64 + tn * 4) = oB;
    }
}

// ---------------------------------------------------------------------------
// 2) f[b,t,l] = x[b,l,:] . Wroot[t,:] + broot[t]
// ---------------------------------------------------------------------------
__global__ __launch_bounds__(256) void f_kernel(const float* __restrict__ x,
    const float* __restrict__ Wroot, const float* __restrict__ broot,
    float* __restrict__ fout) {
  int row = blockIdx.x * 256 + threadIdx.x;   // b*512+l
  int b = row >> 9, l = row & 511;
  float acc[8] = {0,0,0,0,0,0,0,0};
  const float4* xr = (const float4*)(x + (size_t)row * 768);
  for (int h4 = 0; h4 < 192; h4++) {
    float4 xv = xr[h4];
#pragma unroll
    for (int t = 0; t < 8; t++) {
      float4 wv = ((const float4*)(Wroot + (size_t)t * 768))[h4];
      acc[t] += xv.x * wv.x + xv.y * wv.y + xv.z * wv.z + xv.w * wv.w;
    }
  }
#pragma unroll
  for (int t = 0; t < 8; t++)
    fout[(size_t)((b * 8 + t) << 9) + l] = acc[t] + broot[t];
}

// ---------------------------------------------------------------------------
// 3) scores -> softmax -> A = exp(p)*(1-eye). Register-lean; XCD-chunked.
// ---------------------------------------------------------------------------
__global__ __launch_bounds__(256) void scores_kernel(const float* __restrict__ Qb,
    const float* __restrict__ Kb, const int* __restrict__ mask,
    float* __restrict__ A) {
  const int lin = blockIdx.x;                 // 8192 blocks
  const int xcd = lin & 7;
  const int idx = lin >> 3;
  const int bt  = xcd * 32 + (idx >> 5);
  const int q0  = (idx & 31) * 16;
  const int b = bt >> 3, t = bt & 7;
  __shared__ float  S[16][512];
  __shared__ float4 Qs4[16][24];
  __shared__ float  part[16][16];
  __shared__ float  invsum[16];
  const int tid = threadIdx.x;
  for (int i = tid; i < 384; i += 256) {
    int q = i / 24, f4 = i % 24;
    Qs4[q][f4] =
        ((const float4*)(Qb + (size_t)(b * 512 + q0 + q) * 768 + t * 96))[f4];
  }
  __syncthreads();
  const float scl = 0.10206207261596575f;     // 1/sqrt(96)
#pragma unroll 1
  for (int rep = 0; rep < 2; rep++) {
    const int k = rep * 256 + tid;
    const float4* kr = (const float4*)(Kb + (size_t)(b * 512 + k) * 768 + t * 96);
    float acc[16];
#pragma unroll
    for (int q = 0; q < 16; q++) acc[q] = 0.f;
#pragma unroll 4
    for (int f4 = 0; f4 < 24; f4++) {
      float4 kv = kr[f4];
#pragma unroll
      for (int q = 0; q < 16; q++) {
        float4 qv = Qs4[q][f4];
        acc[q] += qv.x * kv.x + qv.y * kv.y + qv.z * kv.z + qv.w * kv.w;
      }
    }
    int mk = mask[b * 512 + k];
#pragma unroll
    for (int q = 0; q < 16; q++)
      S[q][k] = mk ? expf(acc[q] * scl) : 0.f;
  }
  __syncthreads();
  { int q = tid >> 4, j = tid & 15;
    float s = 0.f;
#pragma unroll
    for (int i = 0; i < 32; i++) s += S[q][j + 16 * i];
    part[q][j] = s; }
  __syncthreads();
  if (tid < 16) {
    float s = 0.f;
#pragma unroll
    for (int j = 0; j < 16; j++) s += part[tid][j];
    invsum[tid] = 1.f / fmaxf(s, 1e-30f);
  }
  __syncthreads();
#pragma unroll 1
  for (int rep = 0; rep < 2; rep++) {
    const int k = rep * 256 + tid;
#pragma unroll
    for (int q = 0; q < 16; q++) {
      float p = S[q][k] * invsum[q];
      float a = (q0 + q == k) ? 0.f : expf(p);
      A[(size_t)(bt * 512 + q0 + q) * 512 + k] = a;
    }
  }
}

// ---------------------------------------------------------------------------
// 4+5 fused) deg + build: thread owns column k; one pass over A computes
//    M[q][k] = -A[q][k] (row0 = f) while accumulating deg; diag <- deg.
// ---------------------------------------------------------------------------
__global__ __launch_bounds__(256) void build_kernel(const float* __restrict__ A,
    const float* __restrict__ fin, float* __restrict__ M) {
  const int bt = blockIdx.y;
  const int k = blockIdx.x * 256 + threadIdx.x;
  const float* Ab = A + (size_t)bt * 262144;
  float* Mb = M + (size_t)bt * 262144;
  float s = 0.f;
  { float a = Ab[k]; s += a; Mb[k] = fin[bt * 512 + k]; }   // row 0 = f
  for (int q = 1; q < 512; q++) {
    float a = Ab[(size_t)q * 512 + k];
    s += a;
    Mb[(size_t)q * 512 + k] = -a;
  }
  if (k != 0) Mb[(size_t)k * 512 + k] = s;    // diag = deg[k] (A diag is 0)
}

// ---------------------------------------------------------------------------
// 6a) Panel factorization + staging (fused). In-place GJ with partial
//     pivoting over 64 pivot columns; 512 threads, one row per thread.
//     After write-back: computes perm, rowslot, and snapshots X rows +
//     moved rows into Stg (races with the row-tiled GEMM update avoided).
// ---------------------------------------------------------------------------
__global__ __launch_bounds__(512) void panel_kernel(float* __restrict__ M,
    int* __restrict__ pivr, float* __restrict__ Stg, int* __restrict__ rowslot,
    int ph) {
  const int bt = blockIdx.x, tid = threadIdx.x;
  const int j0 = ph * NB_;
  __shared__ float rowj[NB_];
  __shared__ float bufj[NB_], bufr[NB_];
  __shared__ float pivval_s;
  __shared__ unsigned long long wred[8];
  __shared__ int pivlist[NB_];
  __shared__ int perm_s[512];
  __shared__ int srcrow[128];
  __shared__ int cnt;
  float* Mb = M + (size_t)bt * 262144;
  float r[NB_];
  {
    const float4* p0 = (const float4*)(Mb + (size_t)tid * 512 + j0);
#pragma unroll
    for (int fi = 0; fi < 16; fi++) {
      float4 a = p0[fi];
      r[4*fi] = a.x; r[4*fi+1] = a.y; r[4*fi+2] = a.z; r[4*fi+3] = a.w;
    }
  }
  const int lane = tid & 63, wv = tid >> 6;
  for (int l = 0; l < NB_; l++) {
    const int j = j0 + l;
    float v = 0.f;
#pragma unroll
    for (int c = 0; c < NB_; c++) v = (c == l) ? r[c] : v;
    float best = -1.f; int bidx = 0;
    if (tid >= j) { best = fabsf(v); bidx = tid; }
    unsigned long long pk = (best >= 0.f)
        ? ((((unsigned long long)__float_as_uint(best)) << 32) | (unsigned)bidx) : 0ull;
#pragma unroll
    for (int off = 32; off > 0; off >>= 1) {
      unsigned long long o = __shfl_xor(pk, off, 64);
      if (o > pk) pk = o;
    }
    if (lane == 0) wred[wv] = pk;
    __syncthreads();
    unsigned long long ma = wred[0];
#pragma unroll
    for (int w = 1; w < 8; w++) ma = (wred[w] > ma) ? wred[w] : ma;
    const int rr = (int)(unsigned)(ma & 0xffffffffull);
    if (tid == rr) {
      pivval_s = v;
#pragma unroll
      for (int c = 0; c < NB_; c++) bufr[c] = r[c];
    }
    if (tid == j) {
#pragma unroll
      for (int c = 0; c < NB_; c++) bufj[c] = r[c];
    }
    if (tid == 0) pivlist[l] = rr;
    __syncthreads();
    const float rinv = 1.f / pivval_s;
    if (tid == j) {
#pragma unroll
      for (int c = 0; c < NB_; c++) {
        float nv = (c == l) ? rinv : bufr[c] * rinv;
        r[c] = nv;
        rowj[c] = nv;
      }
    }
    if (rr != j && tid == rr) {
#pragma unroll
      for (int c = 0; c < NB_; c++) r[c] = bufj[c];
    }
    __syncthreads();
    if (tid != j) {
      float m = 0.f;
#pragma unroll
      for (int c = 0; c < NB_; c++) m = (c == l) ? r[c] : m;
#pragma unroll
      for (int c = 0; c < NB_; c++) r[c] = ((c == l) ? 0.f : r[c]) - m * rowj[c];
    }
    __syncthreads();
  }
  {
    float4* p0 = (float4*)(Mb + (size_t)tid * 512 + j0);
#pragma unroll
    for (int fi = 0; fi < 16; fi++) {
      float4 a = {r[4*fi], r[4*fi+1], r[4*fi+2], r[4*fi+3]};
      p0[fi] = a;
    }
  }
  if (tid < NB_) pivr[bt * 512 + j0 + tid] = pivlist[tid];

  // ----- staging (was stage_kernel) -----
  if (tid < 512) perm_s[tid] = tid;
  if (tid == 0) cnt = 0;
  __syncthreads();          // also drains panel write-back (vmcnt)
  if (tid == 0) {
    for (int l = 0; l < NB_; l++) {
      int rw = pivlist[l];
      int tp = perm_s[j0 + l]; perm_s[j0 + l] = perm_s[rw]; perm_s[rw] = tp;
    }
  }
  __syncthreads();
  {
    int s = -1;
    if (perm_s[tid] != tid) { s = atomicAdd(&cnt, 1); srcrow[s] = perm_s[tid]; }
    rowslot[bt * 512 + tid] = s;
  }
  __syncthreads();
  const int nmv = cnt;   // <= 128
  float* Sb = Stg + (size_t)bt * 98304;       // 192*512 floats per bt
  // X rows: Sb[l][:] = M[perm[j0+l]][:]
  for (int idx = tid; idx < 64 * 128; idx += 512) {
    int l = idx >> 7, f4 = idx & 127;
    ((float4*)(Sb + (size_t)l * 512))[f4] =
        ((const float4*)(Mb + (size_t)perm_s[j0 + l] * 512))[f4];
  }
  // moved rows: Sb[64+s][:] = M[srcrow[s]][:]
  for (int idx = tid; idx < nmv * 128; idx += 512) {
    int s = idx >> 7, f4 = idx & 127;
    ((float4*)(Sb + (size_t)(64 + s) * 512))[f4] =
        ((const float4*)(Mb + (size_t)srcrow[s] * 512))[f4];
  }
}

// ---------------------------------------------------------------------------
// 6b) Rest-of-matrix update as a tiled GEMM:
//     M[i][c] = old(i,c) + V(128xK=64) . X(64x64) - [i in pivot block]*X[i-j0][c]
//     old(i,c) = moved ? Stg[64+slot][c] : M[i][c];  X rows from Stg[0..64).
//     Grid: 256 bt * 4 row-tiles * 7 col-tiles (panel col-tile skipped).
// ---------------------------------------------------------------------------
__global__ __launch_bounds__(256) void update_kernel(float* __restrict__ M,
    const float* __restrict__ Stg, const int* __restrict__ rowslot, int ph) {
  const int lin = blockIdx.x;                 // 7168 blocks
  const int xcd = lin & 7;
  const int idx = lin >> 3;                   // 0..895
  const int bt  = xcd * 32 + (idx / 28);
  const int tl  = idx % 28;
  const int rt  = tl / 7;                     // row-tile 0..3
  int ct = tl % 7;                            // col-tile, skip panel tile
  ct += (ct >= ph) ? 1 : 0;
  const int i0 = rt * 128, c0 = ct * 64;
  const int j0 = ph * NB_;
  float* Mb = M + (size_t)bt * 262144;
  const float* Sb = Stg + (size_t)bt * 98304;
  __shared__ float Vs[16][132];
  __shared__ float Xs[16][68];
  __shared__ int rs_s[128];
  const int tid = threadIdx.x;
  const int tm = tid & 15, tn = tid >> 4;
  if (tid < 128) rs_s[tid] = rowslot[bt * 512 + i0 + tid];
  float acc[8][4];
#pragma unroll
  for (int i = 0; i < 8; i++)
#pragma unroll
    for (int j = 0; j < 4; j++) acc[i][j] = 0.f;

#pragma unroll 1
  for (int kk = 0; kk < 64; kk += 16) {
#pragma unroll
    for (int rep = 0; rep < 2; rep++) {       // V chunk: 128 rows x 16 K
      int fidx = tid + rep * 256;
      int row = fidx >> 2, f4i = fidx & 3;
      float4 v = *(const float4*)(Mb + (size_t)(i0 + row) * 512 + j0 + kk + f4i * 4);
      Vs[f4i * 4 + 0][row] = v.x; Vs[f4i * 4 + 1][row] = v.y;
      Vs[f4i * 4 + 2][row] = v.z; Vs[f4i * 4 + 3][row] = v.w;
    }
    {                                          // X chunk: 16 K-rows x 64 cols
      int row = tid >> 4, f4i = tid & 15;
      float4 v = *(const float4*)(Sb + (size_t)(kk + row) * 512 + c0 + f4i * 4);
      *(float4*)&Xs[row][f4i * 4] = v;
    }
    __syncthreads();
#pragma unroll
    for (int k = 0; k < 16; k++) {
      float4 a0 = *(const float4*)&Vs[k][tm * 4];
      float4 a1 = *(const float4*)&Vs[k][tm * 4 + 64];
      float4 bv = *(const float4*)&Xs[k][tn * 4];
      float am[8] = {a0.x,a0.y,a0.z,a0.w,a1.x,a1.y,a1.z,a1.w};
      float bn[4] = {bv.x,bv.y,bv.z,bv.w};
#pragma unroll
      for (int i = 0; i < 8; i++)
#pragma unroll
        for (int j = 0; j < 4; j++) acc[i][j] += am[i] * bn[j];
    }
    __syncthreads();
  }
  const int colg = c0 + tn * 4;
#pragma unroll
  for (int half = 0; half < 2; half++)
#pragma unroll
    for (int i = 0; i < 4; i++) {
      const int rl = half * 64 + tm * 4 + i;
      const int row = i0 + rl;
      const int rs = rs_s[rl];
      const float* oldp = (rs >= 0) ? (Sb + (size_t)(64 + rs) * 512 + colg)
                                    : (Mb + (size_t)row * 512 + colg);
      float4 o = *(const float4*)oldp;
      o.x += acc[half*4+i][0]; o.y += acc[half*4+i][1];
      o.z += acc[half*4+i][2]; o.w += acc[half*4+i][3];
      if (row >= j0 && row < j0 + NB_) {
        float4 xr = *(const float4*)(Sb + (size_t)(row - j0) * 512 + colg);
        o.x -= xr.x; o.y -= xr.y; o.z -= xr.z; o.w -= xr.w;
      }
      *(float4*)(Mb + (size_t)row * 512 + colg) = o;
    }
}

// 7) column unscramble map (csrc only; diag comes from permute_kernel)
__global__ __launch_bounds__(64) void colsrc_kernel(const int* __restrict__ pivr,
                                                    int* __restrict__ colsrc) {
  const int bt = blockIdx.x, tid = threadIdx.x;
  __shared__ int piv[512];
  __shared__ int cs[512];
  for (int i = tid; i < 512; i += 64) { piv[i] = pivr[bt * 512 + i]; cs[i] = i; }
  __syncthreads();
  if (tid == 0) {
    for (int j = 511; j >= 0; j--) { int r = piv[j]; int tp = cs[j]; cs[j] = cs[r]; cs[r] = tp; }
  }
  __syncthreads();
  for (int i = tid; i < 512; i += 64) colsrc[bt * 512 + i] = cs[i];
}

// ---------------------------------------------------------------------------
// 7b) In-place column unscramble of M: M[row][q] <- M[row][cs[q]].
//     One wave per row via LDS row buffer; emits diag (= new M[i][i]).
//     Makes final_kernel's LLinv reads fully coalesced.
// ---------------------------------------------------------------------------
__global__ __launch_bounds__(256) void permute_kernel(float* __restrict__ M,
    const int* __restrict__ colsrc, float* __restrict__ diagv) {
  const int bt = blockIdx.y, r0 = blockIdx.x * 32;
  __shared__ int cs[512];
  __shared__ float rowbuf[4][512];
  const int tid = threadIdx.x;
  const int lane = tid & 63, w = tid >> 6;
  for (int i = tid; i < 512; i += 256) cs[i] = colsrc[bt * 512 + i];
  __syncthreads();
  float* Mb = M + (size_t)bt * 262144;
  for (int it = 0; it < 8; it++) {
    const int row = r0 + it * 4 + w;
    float4 v0 = ((const float4*)(Mb + (size_t)row * 512))[lane];
    float4 v1 = ((const float4*)(Mb + (size_t)row * 512))[lane + 64];
    *(float4*)&rowbuf[w][lane * 4] = v0;
    *(float4*)&rowbuf[w][256 + lane * 4] = v1;
    __syncthreads();
    float o[8];
#pragma unroll
    for (int j = 0; j < 8; j++) o[j] = rowbuf[w][cs[lane * 8 + j]];
    if ((row >> 3) == lane) {
#pragma unroll
      for (int j = 0; j < 8; j++)
        if ((row & 7) == j) diagv[bt * 512 + row] = o[j];
    }
    float4 oA = {o[0], o[1], o[2], o[3]};
    float4 oB = {o[4], o[5], o[6], o[7]};
    *(float4*)(Mb + (size_t)row * 512 + lane * 8) = oA;
    *(float4*)(Mb + (size_t)row * 512 + lane * 8 + 4) = oB;
    __syncthreads();
  }
}

// ---------------------------------------------------------------------------
// 8) Final: att[k,q] = (k!=0)*A[q,k]*diag[k] - (q!=0)*A[q,k]*LLinv[k,q]
//    M is column-unscrambled, so LLinv[k,q] = M[k][q] (coalesced).
// ---------------------------------------------------------------------------
__global__ __launch_bounds__(256) void final_kernel(const float* __restrict__ M,
    const float* __restrict__ diagv, float* __restrict__ Aout) {
  const int bt = blockIdx.y;
  int x = blockIdx.x, ti = 0;
  while (x >= 8 - ti) { x -= 8 - ti; ti++; }
  const int tj = ti + x;
  const int tid = threadIdx.x, c = tid & 63, g = tid >> 6;
  __shared__ float Aa[64][65];
  __shared__ float Ab[64][65];
  __shared__ float dgi[64], dgj[64];
  const size_t base = (size_t)bt * 262144;
  const float* Mb = M + base;
  float* Ao = Aout + base;
  if (tid < 64)       dgi[tid] = diagv[bt * 512 + ti * 64 + tid];
  else if (tid < 128) dgj[tid - 64] = diagv[bt * 512 + tj * 64 + (tid - 64)];
  for (int rr = g; rr < 64; rr += 4)
    Aa[rr][c] = Ao[(size_t)(tj * 64 + rr) * 512 + ti * 64 + c];
  if (ti != tj)
    for (int rr = g; rr < 64; rr += 4)
      Ab[rr][c] = Ao[(size_t)(ti * 64 + rr) * 512 + tj * 64 + c];
  __syncthreads();
  for (int kk = g; kk < 64; kk += 4) {               // O1: rows Ti, cols Tj
    int krow = ti * 64 + kk, q = tj * 64 + c;
    float a = Aa[c][kk];
    float llv = Mb[(size_t)krow * 512 + q];
    float val = 0.f;
    if (krow != 0) val = a * dgi[kk];
    if (q != 0)    val -= a * llv;
    Ao[(size_t)krow * 512 + q] = val;
  }
  if (ti != tj) {
    for (int kk = g; kk < 64; kk += 4) {             // O2: rows Tj, cols Ti
      int krow = tj * 64 + kk, q = ti * 64 + c;
      float a = Ab[c][kk];
      float llv = Mb[(size_t)krow * 512 + q];
      float val = 0.f;
      if (krow != 0) val = a * dgj[kk];
      if (q != 0)    val -= a * llv;
      Ao[(size_t)krow * 512 + q] = val;
    }
  }
}

// ---------------------------------------------------------------------------
extern "C" void kernel_launch(void* const* d_in, const int* in_sizes, int n_in,
                              void* d_out, int out_size, void* d_ws, size_t ws_size,
                              hipStream_t stream) {
  const float* x     = (const float*)d_in[0];
  const int*   mask  = (const int*)d_in[1];
  const float* Wq    = (const float*)d_in[2];
  const float* bq    = (const float*)d_in[3];
  const float* Wk    = (const float*)d_in[4];
  const float* bk    = (const float*)d_in[5];
  const float* Wroot = (const float*)d_in[6];
  const float* broot = (const float*)d_in[7];
  float* A = (float*)d_out;                    // holds exp(p_attn) then final att

  float* ws = (float*)d_ws;
  size_t off = 0;
  float* M    = ws + off; off += (size_t)256 * 512 * 512;   // 256 MB
  float* Qb   = ws + off; off += (size_t)16384 * 768;       // 50 MB
  float* Kb   = ws + off; off += (size_t)16384 * 768;       // 50 MB
  float* fbuf = ws + off; off += (size_t)256 * 512;
  float* dgv  = ws + off; off += (size_t)256 * 512;
  int* pivr   = (int*)(ws + off); off += (size_t)256 * 512;
  int* csrc   = (int*)(ws + off); off += (size_t)256 * 512;
  int* rslot  = (int*)(ws + off); off += (size_t)256 * 512;
  if (ws_size < off * sizeof(float)) return;   // workspace too small: visible failure

  // Stage buffer (192 rows x 512 cols x 256 bt = 100 MB) aliases Qb+Kb,
  // which are dead after scores_kernel.
  float* Stg = Qb;

  proj_gemm<<<dim3(128, 6, 2), 256, 0, stream>>>(x, Wq, bq, Wk, bk, Qb, Kb);
  f_kernel<<<64, 256, 0, stream>>>(x, Wroot, broot, fbuf);
  scores_kernel<<<dim3(8192), 256, 0, stream>>>(Qb, Kb, mask, A);
  build_kernel<<<dim3(2, 256), 256, 0, stream>>>(A, fbuf, M);
  for (int ph = 0; ph < NPH; ph++) {
    panel_kernel<<<256, 512, 0, stream>>>(M, pivr, Stg, rslot, ph);
    update_kernel<<<dim3(7168), 256, 0, stream>>>(M, Stg, rslot, ph);
  }
  colsrc_kernel<<<256, 64, 0, stream>>>(pivr, csrc);
  permute_kernel<<<dim3(16, 256), 256, 0, stream>>>(M, csrc, dgv);
  final_kernel<<<dim3(36, 256), 256, 0, stream>>>(M, dgv, A);
}